// Round 1
// baseline (2613.480 us; speedup 1.0000x reference)
//
#include <hip/hip_runtime.h>

// Seq2SeqDecoder: 2-layer GRU (reset_after) + logit projection, MI355X/gfx950.
// B=32 T=64 V=32000 E=512 H=1024. Plan:
//   phase 0: transpose-convert weights to bf16 [N][K]; build xin bf16; init states
//   phase 1: MX  = xin @ k0t + b0[0]            (bf16 MFMA GEMM, 19.3 GF)
//   phase 2: 64x fused cell0 (mi=h0@rk0, gate)  -> seq0, h0 chain
//   phase 3: MX  = seq0 @ k1t + b1[0]           (12.9 GF)
//   phase 4: 64x fused cell1                    -> seq1, h1 chain
//   phase 5: logits = seq1 @ Wdt + bd           (134.2 GF) -> d_out
//   phase 6: final states -> d_out tail

typedef __attribute__((ext_vector_type(8))) short bf16x8;
typedef __attribute__((ext_vector_type(4))) float f32x4;
typedef unsigned short u16;

__device__ __forceinline__ u16 f2bf(float f) {
  unsigned int x = __float_as_uint(f);
  x += 0x7fffu + ((x >> 16) & 1u);   // RNE
  return (u16)(x >> 16);
}

// ---- transpose + convert: in f32 [R][C] -> out bf16 [C][R] ----------------
__global__ void k_tconv(const float* __restrict__ in, u16* __restrict__ out,
                        int R, int C) {
  __shared__ float t[32][33];
  int tx = threadIdx.x, ty = threadIdx.y;          // 32 x 8
  int c0 = blockIdx.x * 32, r0 = blockIdx.y * 32;
#pragma unroll
  for (int i = 0; i < 4; ++i)
    t[ty + i * 8][tx] = in[(long)(r0 + ty + i * 8) * C + c0 + tx];
  __syncthreads();
#pragma unroll
  for (int i = 0; i < 4; ++i)
    out[(long)(c0 + ty + i * 8) * R + r0 + tx] = f2bf(t[tx][ty + i * 8]);
}

// ---- xin[bt][0:512]=emb[X[bt]], [512:1536]=state[1][b]  (bf16) ------------
__global__ void k_embed(const int* __restrict__ X, const float* __restrict__ state,
                        const float* __restrict__ emb, u16* __restrict__ xin) {
  int bt = blockIdx.x;
  int b = bt >> 6;
  int tok = X[bt];
  const float* er = emb + (long)tok * 512;
  const float* cr = state + 32 * 1024 + b * 1024;  // state[-1] == state[1]
  for (int c = threadIdx.x; c < 1536; c += 256) {
    float v = (c < 512) ? er[c] : cr[c - 512];
    xin[(long)bt * 1536 + c] = f2bf(v);
  }
}

__global__ void k_init(const float* __restrict__ state, float* h0, u16* h0b,
                       float* h1, u16* h1b) {
  int i = blockIdx.x * 256 + threadIdx.x;          // grid 128 -> 32768
  float v0 = state[i], v1 = state[32768 + i];
  h0[i] = v0; h0b[i] = f2bf(v0);
  h1[i] = v1; h1b[i] = f2bf(v1);
}

// ---- bf16 GEMM: C[M,N]f32 = A[M,K] @ Bt[N,K]^T + bias[N] ------------------
// 128x128 tile, BK=32, 256 thr = 4 waves (wave quadrant 64x64, 4x4 mfma tiles)
__global__ void k_gemm(const u16* __restrict__ A, const u16* __restrict__ Bt,
                       const float* __restrict__ bias, float* __restrict__ C,
                       int M, int N, int K) {
  __shared__ u16 As[128][40];   // pad 32->40 elems: 2-way-max bank aliasing
  __shared__ u16 Bs[128][40];
  int tid = threadIdx.x;
  int w = tid >> 6, l = tid & 63;
  int ln = l & 15, lk = l >> 4;
  int r0 = blockIdx.y * 128, c0 = blockIdx.x * 128;
  int qr = (w & 1) * 64, qc = (w >> 1) * 64;
  int sr = tid >> 1, sc = (tid & 1) * 16;
  const u16* Ap = A + (long)(r0 + sr) * K + sc;
  const u16* Bp = Bt + (long)(c0 + sr) * K + sc;
  f32x4 acc[4][4] = {};
  for (int kt = 0; kt < K; kt += 32) {
    bf16x8 a0 = *(const bf16x8*)(Ap + kt);
    bf16x8 a1 = *(const bf16x8*)(Ap + kt + 8);
    bf16x8 b0 = *(const bf16x8*)(Bp + kt);
    bf16x8 b1 = *(const bf16x8*)(Bp + kt + 8);
    __syncthreads();
    *(bf16x8*)(&As[sr][sc]) = a0;  *(bf16x8*)(&As[sr][sc + 8]) = a1;
    *(bf16x8*)(&Bs[sr][sc]) = b0;  *(bf16x8*)(&Bs[sr][sc + 8]) = b1;
    __syncthreads();
    bf16x8 af[4], bfv[4];
#pragma unroll
    for (int mt = 0; mt < 4; ++mt)
      af[mt] = *(const bf16x8*)(&As[qr + mt * 16 + ln][lk * 8]);
#pragma unroll
    for (int nt = 0; nt < 4; ++nt)
      bfv[nt] = *(const bf16x8*)(&Bs[qc + nt * 16 + ln][lk * 8]);
#pragma unroll
    for (int mt = 0; mt < 4; ++mt)
#pragma unroll
      for (int nt = 0; nt < 4; ++nt)
        acc[mt][nt] = __builtin_amdgcn_mfma_f32_16x16x32_bf16(
            af[mt], bfv[nt], acc[mt][nt], 0, 0, 0);
  }
#pragma unroll
  for (int mt = 0; mt < 4; ++mt)
#pragma unroll
    for (int nt = 0; nt < 4; ++nt)
#pragma unroll
      for (int r = 0; r < 4; ++r) {
        int row = r0 + qr + mt * 16 + lk * 4 + r;
        int col = c0 + qc + nt * 16 + ln;
        C[(long)row * N + col] = acc[mt][nt][r] + bias[col];
      }
}

// ---- fused GRU cell: mi = h @ W (bf16 MFMA) + reset_after gating ----------
// grid 32 blocks (32 h-cols each), 256 thr = 4 waves: (row-tile rt) x (K-half kh)
// wave computes 16 rows x {z,r,h}x32 cols over K/2; kh=1 partials reduced via LDS.
__global__ void k_cell(const u16* __restrict__ Wt,   // [3072][1024] bf16 (rk^T)
                       const float* __restrict__ MX, // [2048][3072] mx(+b[0])
                       const float* __restrict__ bias, // b[1] (3072)
                       const float* __restrict__ h_in, const u16* __restrict__ hb_in,
                       float* __restrict__ h_out, u16* __restrict__ hb_out,
                       u16* __restrict__ seq_out,    // [2048][1024]
                       int t) {
  __shared__ float red[2][6][4][64];
  int tid = threadIdx.x;
  int w = tid >> 6, l = tid & 63;
  int ln = l & 15, lk = l >> 4;
  int rt = w & 1, kh = w >> 1;
  int j0 = blockIdx.x * 32;
  f32x4 acc[3][2] = {};
  const u16* hp = hb_in + (rt * 16 + ln) * 1024 + kh * 512 + lk * 8;
  const u16* wp = Wt + (long)(j0 + ln) * 1024 + kh * 512 + lk * 8;
#pragma unroll 4
  for (int s = 0; s < 16; ++s) {
    bf16x8 a = *(const bf16x8*)(hp + s * 32);
#pragma unroll
    for (int g = 0; g < 3; ++g)
#pragma unroll
      for (int c = 0; c < 2; ++c) {
        bf16x8 bv = *(const bf16x8*)(wp + ((long)g << 20) + (c << 14) + s * 32);
        acc[g][c] = __builtin_amdgcn_mfma_f32_16x16x32_bf16(a, bv, acc[g][c], 0, 0, 0);
      }
  }
  if (kh == 1) {
#pragma unroll
    for (int g = 0; g < 3; ++g)
#pragma unroll
      for (int c = 0; c < 2; ++c)
#pragma unroll
        for (int r = 0; r < 4; ++r)
          red[rt][g * 2 + c][r][l] = acc[g][c][r];
  }
  __syncthreads();
  if (kh == 0) {
#pragma unroll
    for (int c = 0; c < 2; ++c)
#pragma unroll
      for (int r = 0; r < 4; ++r) {
        int row = rt * 16 + lk * 4 + r;          // batch index b
        int j = j0 + c * 16 + ln;                // h column
        float miz = acc[0][c][r] + red[rt][0 + c][r][l] + bias[j];
        float mir = acc[1][c][r] + red[rt][2 + c][r][l] + bias[1024 + j];
        float mih = acc[2][c][r] + red[rt][4 + c][r][l] + bias[2048 + j];
        long mrow = (long)row * 64 + t;          // b*T + t
        float mxz = MX[mrow * 3072 + j];
        float mxr = MX[mrow * 3072 + 1024 + j];
        float mxh = MX[mrow * 3072 + 2048 + j];
        float z = 1.f / (1.f + expf(-(mxz + miz)));
        float rg = 1.f / (1.f + expf(-(mxr + mir)));
        float hh = tanhf(mxh + rg * mih);
        float hold = h_in[row * 1024 + j];
        float hn = z * hold + (1.f - z) * hh;
        h_out[row * 1024 + j] = hn;
        u16 hb = f2bf(hn);
        hb_out[row * 1024 + j] = hb;
        seq_out[mrow * 1024 + j] = hb;
      }
  }
}

__global__ void k_states(const float* __restrict__ h0, const float* __restrict__ h1,
                         float* __restrict__ out) {
  int i = blockIdx.x * 256 + threadIdx.x;        // grid 128
  out[i] = h0[i];
  out[32768 + i] = h1[i];
}

extern "C" void kernel_launch(void* const* d_in, const int* in_sizes, int n_in,
                              void* d_out, int out_size, void* d_ws, size_t ws_size,
                              hipStream_t stream) {
  const int*   X     = (const int*)  d_in[0];
  const float* state = (const float*)d_in[1];
  const float* emb   = (const float*)d_in[2];
  const float* k0    = (const float*)d_in[3];
  const float* rk0   = (const float*)d_in[4];
  const float* b0    = (const float*)d_in[5];
  const float* k1    = (const float*)d_in[6];
  const float* rk1   = (const float*)d_in[7];
  const float* b1    = (const float*)d_in[8];
  const float* Wd    = (const float*)d_in[9];
  const float* bd    = (const float*)d_in[10];
  float* out = (float*)d_out;

  char* p = (char*)d_ws;
  size_t off = 0;
  auto alloc = [&](size_t bytes) {
    char* r = p + off;
    off += (bytes + 255) & ~(size_t)255;
    return r;
  };
  u16* k0t  = (u16*)alloc(3072UL * 1536 * 2);
  u16* rk0t = (u16*)alloc(3072UL * 1024 * 2);
  u16* k1t  = (u16*)alloc(3072UL * 1024 * 2);
  u16* rk1t = (u16*)alloc(3072UL * 1024 * 2);
  u16* Wdt  = (u16*)alloc(32000UL * 1024 * 2);
  u16* xin  = (u16*)alloc(2048UL * 1536 * 2);
  float* MX = (float*)alloc(2048UL * 3072 * 4);
  u16* seq0 = (u16*)alloc(2048UL * 1024 * 2);
  u16* seq1 = (u16*)alloc(2048UL * 1024 * 2);
  float* h0f0 = (float*)alloc(32768 * 4); float* h0f1 = (float*)alloc(32768 * 4);
  float* h1f0 = (float*)alloc(32768 * 4); float* h1f1 = (float*)alloc(32768 * 4);
  u16* h0b0 = (u16*)alloc(32768 * 2); u16* h0b1 = (u16*)alloc(32768 * 2);
  u16* h1b0 = (u16*)alloc(32768 * 2); u16* h1b1 = (u16*)alloc(32768 * 2);
  if (off > ws_size) return;   // ws too small -> zero output signature (0.5508)

  float* h0f[2] = {h0f0, h0f1}; float* h1f[2] = {h1f0, h1f1};
  u16*   h0b[2] = {h0b0, h0b1}; u16*   h1b[2] = {h1b0, h1b1};

  dim3 tb(32, 8);
  k_tconv<<<dim3(3072 / 32, 1536 / 32), tb, 0, stream>>>(k0, k0t, 1536, 3072);
  k_tconv<<<dim3(3072 / 32, 1024 / 32), tb, 0, stream>>>(rk0, rk0t, 1024, 3072);
  k_tconv<<<dim3(3072 / 32, 1024 / 32), tb, 0, stream>>>(k1, k1t, 1024, 3072);
  k_tconv<<<dim3(3072 / 32, 1024 / 32), tb, 0, stream>>>(rk1, rk1t, 1024, 3072);
  k_tconv<<<dim3(32000 / 32, 1024 / 32), tb, 0, stream>>>(Wd, Wdt, 1024, 32000);
  k_embed<<<2048, 256, 0, stream>>>(X, state, emb, xin);
  k_init<<<128, 256, 0, stream>>>(state, h0f[0], h0b[0], h1f[0], h1b[0]);

  // phase 1: MX = xin @ k0t + b0[0]
  k_gemm<<<dim3(24, 16), 256, 0, stream>>>(xin, k0t, b0, MX, 2048, 3072, 1536);

  // phase 2: layer-0 chain
  for (int t = 0; t < 64; ++t) {
    int c = t & 1, n = c ^ 1;
    k_cell<<<32, 256, 0, stream>>>(rk0t, MX, b0 + 3072, h0f[c], h0b[c],
                                   h0f[n], h0b[n], seq0, t);
  }
  // phase 3: MX = seq0 @ k1t + b1[0]
  k_gemm<<<dim3(24, 16), 256, 0, stream>>>(seq0, k1t, b1, MX, 2048, 3072, 1024);

  // phase 4: layer-1 chain
  for (int t = 0; t < 64; ++t) {
    int c = t & 1, n = c ^ 1;
    k_cell<<<32, 256, 0, stream>>>(rk1t, MX, b1 + 3072, h1f[c], h1b[c],
                                   h1f[n], h1b[n], seq1, t);
  }
  // phase 5: logits
  k_gemm<<<dim3(32000 / 128, 16), 256, 0, stream>>>(seq1, Wdt, bd, out,
                                                    2048, 32000, 1024);
  // phase 6: final states (after 64 steps, parity lands back in buffer 0)
  k_states<<<128, 256, 0, stream>>>(h0f[0], h1f[0], out + 65536000UL);
}

// Round 2
// 2531.356 us; speedup vs baseline: 1.0324x; 1.0324x over previous
//
#include <hip/hip_runtime.h>
#include <hip/hip_cooperative_groups.h>

namespace cg = cooperative_groups;

// Seq2SeqDecoder: 2-layer GRU (reset_after) + logit projection, MI355X/gfx950.
// B=32 T=64 V=32000 E=512 H=1024.
//   phase 0: transpose-convert weights to bf16 [N][K]; build xin bf16; init states
//   phase 1: MX0 = xin @ k0t + b0[0]                  (bf16 MFMA GEMM, 19.3 GF)
//   phase 2: ONE cooperative persistent kernel runs the whole recurrence:
//            66 pipeline steps, grid.sync() between; block types
//            L0 (h0@rk0+gate), MX1 (h0@k1+b1[0]), L1 (h1@rk1+gate)
//   phase 3: logits = seq1 @ Wdt + bd                 (134.2 GF) -> d_out
//   phase 4: final states -> d_out tail

typedef __attribute__((ext_vector_type(8))) short bf16x8;
typedef __attribute__((ext_vector_type(4))) float f32x4;
typedef unsigned short u16;

__device__ __forceinline__ u16 f2bf(float f) {
  unsigned int x = __float_as_uint(f);
  x += 0x7fffu + ((x >> 16) & 1u);   // RNE
  return (u16)(x >> 16);
}

// ---- transpose + convert: in f32 [R][C] -> out bf16 [C][R] ----------------
__global__ void k_tconv(const float* __restrict__ in, u16* __restrict__ out,
                        int R, int C) {
  __shared__ float t[32][33];
  int tx = threadIdx.x, ty = threadIdx.y;          // 32 x 8
  int c0 = blockIdx.x * 32, r0 = blockIdx.y * 32;
#pragma unroll
  for (int i = 0; i < 4; ++i)
    t[ty + i * 8][tx] = in[(long)(r0 + ty + i * 8) * C + c0 + tx];
  __syncthreads();
#pragma unroll
  for (int i = 0; i < 4; ++i)
    out[(long)(c0 + ty + i * 8) * R + r0 + tx] = f2bf(t[tx][ty + i * 8]);
}

// ---- xin[bt][0:512]=emb[X[bt]], [512:1536]=state[1][b]  (bf16) ------------
__global__ void k_embed(const int* __restrict__ X, const float* __restrict__ state,
                        const float* __restrict__ emb, u16* __restrict__ xin) {
  int bt = blockIdx.x;
  int b = bt >> 6;
  int tok = X[bt];
  const float* er = emb + (long)tok * 512;
  const float* cr = state + 32 * 1024 + b * 1024;  // state[-1] == state[1]
  for (int c = threadIdx.x; c < 1536; c += 256) {
    float v = (c < 512) ? er[c] : cr[c - 512];
    xin[(long)bt * 1536 + c] = f2bf(v);
  }
}

// ---- init: H0 slot0 = bf16(state[0]); parity-1 slots hold h(-1) -----------
__global__ void k_init(const float* __restrict__ state, u16* __restrict__ H0,
                       u16* __restrict__ H1, float* __restrict__ h0f,
                       float* __restrict__ h1f) {
  int i = blockIdx.x * 256 + threadIdx.x;          // grid 128 -> 32768
  float v0 = state[i], v1 = state[32768 + i];
  H0[i] = f2bf(v0);             // H0 slot 0  (holds h0(-1))
  h0f[32768 + i] = v0;          // parity 1
  H1[32768 + i] = f2bf(v1);     // parity 1   (holds h1(-1))
  h1f[32768 + i] = v1;
}

// ---- bf16 GEMM: C[M,N]f32 = A[M,K] @ Bt[N,K]^T + bias[N] ------------------
// 128x128 tile, BK=32, 256 thr = 4 waves (wave quadrant 64x64, 4x4 mfma tiles)
__global__ void k_gemm(const u16* __restrict__ A, const u16* __restrict__ Bt,
                       const float* __restrict__ bias, float* __restrict__ C,
                       int M, int N, int K) {
  __shared__ u16 As[128][40];
  __shared__ u16 Bs[128][40];
  int tid = threadIdx.x;
  int w = tid >> 6, l = tid & 63;
  int ln = l & 15, lk = l >> 4;
  int r0 = blockIdx.y * 128, c0 = blockIdx.x * 128;
  int qr = (w & 1) * 64, qc = (w >> 1) * 64;
  int sr = tid >> 1, sc = (tid & 1) * 16;
  const u16* Ap = A + (long)(r0 + sr) * K + sc;
  const u16* Bp = Bt + (long)(c0 + sr) * K + sc;
  f32x4 acc[4][4] = {};
  for (int kt = 0; kt < K; kt += 32) {
    bf16x8 a0 = *(const bf16x8*)(Ap + kt);
    bf16x8 a1 = *(const bf16x8*)(Ap + kt + 8);
    bf16x8 b0 = *(const bf16x8*)(Bp + kt);
    bf16x8 b1 = *(const bf16x8*)(Bp + kt + 8);
    __syncthreads();
    *(bf16x8*)(&As[sr][sc]) = a0;  *(bf16x8*)(&As[sr][sc + 8]) = a1;
    *(bf16x8*)(&Bs[sr][sc]) = b0;  *(bf16x8*)(&Bs[sr][sc + 8]) = b1;
    __syncthreads();
    bf16x8 af[4], bfv[4];
#pragma unroll
    for (int mt = 0; mt < 4; ++mt)
      af[mt] = *(const bf16x8*)(&As[qr + mt * 16 + ln][lk * 8]);
#pragma unroll
    for (int nt = 0; nt < 4; ++nt)
      bfv[nt] = *(const bf16x8*)(&Bs[qc + nt * 16 + ln][lk * 8]);
#pragma unroll
    for (int mt = 0; mt < 4; ++mt)
#pragma unroll
      for (int nt = 0; nt < 4; ++nt)
        acc[mt][nt] = __builtin_amdgcn_mfma_f32_16x16x32_bf16(
            af[mt], bfv[nt], acc[mt][nt], 0, 0, 0);
  }
#pragma unroll
  for (int mt = 0; mt < 4; ++mt)
#pragma unroll
    for (int nt = 0; nt < 4; ++nt)
#pragma unroll
      for (int r = 0; r < 4; ++r) {
        int row = r0 + qr + mt * 16 + lk * 4 + r;
        int col = c0 + qc + nt * 16 + ln;
        C[(long)row * N + col] = acc[mt][nt][r] + bias[col];
      }
}

// ---- persistent cooperative recurrence kernel -----------------------------
// grid 192: blocks [0,64)=L0, [64,128)=MX1, [128,192)=L1; each owns 16 h-cols.
// 66 pipeline steps: L0 at t=s, MX1 at t=s-1, L1 at t=s-2; grid.sync between.
// Per step per block: [32,1024]bf16 @ [1024,48]bf16 -> [32,48]f32 (+gate).
// Weights read from L2-resident global (98KB slice stays in own XCD's L2).
// H0: 4-slot rotation, slot (i&3) holds h0(i-1). h0f/h1f/H1/MX1: parity t&1.
__global__ void __launch_bounds__(256, 1)
k_chain(const u16* __restrict__ rk0t, const u16* __restrict__ k1t,
        const u16* __restrict__ rk1t, const float* __restrict__ MX0,
        const float* __restrict__ b0, const float* __restrict__ b1,
        float* __restrict__ MX1, u16* __restrict__ H0, u16* __restrict__ H1,
        float* __restrict__ h0f, float* __restrict__ h1f,
        u16* __restrict__ seq1) {
  __shared__ float red[2][3][4][64];
  cg::grid_group grid = cg::this_grid();
  const int blk = blockIdx.x;
  const int type = blk >> 6;          // 0:L0  1:MX1  2:L1
  const int cb = blk & 63;
  const int j0 = cb << 4;             // 16 h-cols per block
  const int tid = threadIdx.x;
  const int w = tid >> 6, l = tid & 63;
  const int ln = l & 15, lk = l >> 4;
  const int rt = w & 1, kh = w >> 1;  // row-tile (16 rows), K-half (512)

  const u16* Wt = (type == 0) ? rk0t : (type == 1) ? k1t : rk1t;
  const u16* wp = Wt + (long)(j0 + ln) * 1024 + kh * 512 + lk * 8;

  for (int s = 0; s < 66; ++s) {
    const int tt = (type == 0) ? s : (type == 1) ? s - 1 : s - 2;
    const bool active = (tt >= 0) && (tt < 64);
    f32x4 acc[3] = {};
    if (active) {
      const u16* Ab =
          (type == 0) ? H0 + (long)(tt & 3) * 32768 :          // h0(t-1)
          (type == 1) ? H0 + (long)((tt + 1) & 3) * 32768 :    // h0(t)
                        H1 + (long)((tt + 1) & 1) * 32768;     // h1(t-1)
      const u16* hp = Ab + (rt * 16 + ln) * 1024 + kh * 512 + lk * 8;
#pragma unroll 4
      for (int ks = 0; ks < 16; ++ks) {
        bf16x8 a = *(const bf16x8*)(hp + ks * 32);
#pragma unroll
        for (int g = 0; g < 3; ++g) {
          bf16x8 bv = *(const bf16x8*)(wp + ((long)g << 20) + ks * 32);
          acc[g] = __builtin_amdgcn_mfma_f32_16x16x32_bf16(a, bv, acc[g], 0, 0, 0);
        }
      }
      if (kh == 1) {
#pragma unroll
        for (int g = 0; g < 3; ++g)
#pragma unroll
          for (int r = 0; r < 4; ++r)
            red[rt][g][r][l] = acc[g][r];
      }
    }
    __syncthreads();
    if (active && kh == 0) {
#pragma unroll
      for (int r = 0; r < 4; ++r) {
        const int row = rt * 16 + lk * 4 + r;    // batch b
        const int j = j0 + ln;
        float mz = acc[0][r] + red[rt][0][r][l];
        float mr = acc[1][r] + red[rt][1][r][l];
        float mh = acc[2][r] + red[rt][2][r][l];
        if (type == 1) {
          float* o = MX1 + (long)(tt & 1) * 98304 + (long)row * 3072;
          o[j]        = mz + b1[j];
          o[1024 + j] = mr + b1[1024 + j];
          o[2048 + j] = mh + b1[2048 + j];
        } else {
          const float* bias = (type == 0) ? b0 + 3072 : b1 + 3072;  // b[1]
          const float* mx =
              (type == 0) ? MX0 + ((long)row * 64 + tt) * 3072
                          : MX1 + (long)(tt & 1) * 98304 + (long)row * 3072;
          float miz = mz + bias[j];
          float mir = mr + bias[1024 + j];
          float mih = mh + bias[2048 + j];
          float z  = 1.f / (1.f + expf(-(mx[j] + miz)));
          float rg = 1.f / (1.f + expf(-(mx[1024 + j] + mir)));
          float hh = tanhf(mx[2048 + j] + rg * mih);
          float* hf = (type == 0) ? h0f : h1f;
          float hold = hf[(long)((tt + 1) & 1) * 32768 + row * 1024 + j];
          float hn = z * hold + (1.f - z) * hh;
          hf[(long)(tt & 1) * 32768 + row * 1024 + j] = hn;
          u16 hb = f2bf(hn);
          if (type == 0) {
            H0[(long)((tt + 1) & 3) * 32768 + row * 1024 + j] = hb;   // h0(t)
          } else {
            H1[(long)(tt & 1) * 32768 + row * 1024 + j] = hb;         // h1(t)
            seq1[((long)row * 64 + tt) * 1024 + j] = hb;
          }
        }
      }
    }
    grid.sync();
  }
}

__global__ void k_states(const float* __restrict__ h0, const float* __restrict__ h1,
                         float* __restrict__ out) {
  int i = blockIdx.x * 256 + threadIdx.x;        // grid 128
  out[i] = h0[i];
  out[32768 + i] = h1[i];
}

extern "C" void kernel_launch(void* const* d_in, const int* in_sizes, int n_in,
                              void* d_out, int out_size, void* d_ws, size_t ws_size,
                              hipStream_t stream) {
  const int*   X     = (const int*)  d_in[0];
  const float* state = (const float*)d_in[1];
  const float* emb   = (const float*)d_in[2];
  const float* k0    = (const float*)d_in[3];
  const float* rk0   = (const float*)d_in[4];
  const float* b0    = (const float*)d_in[5];
  const float* k1    = (const float*)d_in[6];
  const float* rk1   = (const float*)d_in[7];
  const float* b1    = (const float*)d_in[8];
  const float* Wd    = (const float*)d_in[9];
  const float* bd    = (const float*)d_in[10];
  float* out = (float*)d_out;

  char* p = (char*)d_ws;
  size_t off = 0;
  auto alloc = [&](size_t bytes) {
    char* r = p + off;
    off += (bytes + 255) & ~(size_t)255;
    return r;
  };
  u16* k0t  = (u16*)alloc(3072UL * 1536 * 2);
  u16* rk0t = (u16*)alloc(3072UL * 1024 * 2);
  u16* k1t  = (u16*)alloc(3072UL * 1024 * 2);
  u16* rk1t = (u16*)alloc(3072UL * 1024 * 2);
  u16* Wdt  = (u16*)alloc(32000UL * 1024 * 2);
  u16* xin  = (u16*)alloc(2048UL * 1536 * 2);
  float* MX0 = (float*)alloc(2048UL * 3072 * 4);
  float* MX1 = (float*)alloc(2UL * 32 * 3072 * 4);
  u16* H0   = (u16*)alloc(4UL * 32768 * 2);      // 4-slot rotation
  u16* H1   = (u16*)alloc(2UL * 32768 * 2);
  float* h0f = (float*)alloc(2UL * 32768 * 4);
  float* h1f = (float*)alloc(2UL * 32768 * 4);
  u16* seq1 = (u16*)alloc(2048UL * 1024 * 2);
  if (off > ws_size) return;   // ws too small -> poison output signature

  dim3 tb(32, 8);
  k_tconv<<<dim3(3072 / 32, 1536 / 32), tb, 0, stream>>>(k0, k0t, 1536, 3072);
  k_tconv<<<dim3(3072 / 32, 1024 / 32), tb, 0, stream>>>(rk0, rk0t, 1024, 3072);
  k_tconv<<<dim3(3072 / 32, 1024 / 32), tb, 0, stream>>>(k1, k1t, 1024, 3072);
  k_tconv<<<dim3(3072 / 32, 1024 / 32), tb, 0, stream>>>(rk1, rk1t, 1024, 3072);
  k_tconv<<<dim3(32000 / 32, 1024 / 32), tb, 0, stream>>>(Wd, Wdt, 1024, 32000);
  k_embed<<<2048, 256, 0, stream>>>(X, state, emb, xin);
  k_init<<<128, 256, 0, stream>>>(state, H0, H1, h0f, h1f);

  // phase 1: MX0 = xin @ k0t + b0[0]
  k_gemm<<<dim3(24, 16), 256, 0, stream>>>(xin, k0t, b0, MX0, 2048, 3072, 1536);

  // phase 2: full recurrence in one cooperative kernel
  {
    void* args[] = {(void*)&rk0t, (void*)&k1t, (void*)&rk1t, (void*)&MX0,
                    (void*)&b0,   (void*)&b1,  (void*)&MX1,  (void*)&H0,
                    (void*)&H1,   (void*)&h0f, (void*)&h1f,  (void*)&seq1};
    hipLaunchCooperativeKernel((void*)k_chain, dim3(192), dim3(256), args, 0,
                               stream);
  }

  // phase 3: logits = seq1 @ Wdt + bd
  k_gemm<<<dim3(32000 / 128, 16), 256, 0, stream>>>(seq1, Wdt, bd, out,
                                                    2048, 32000, 1024);
  // phase 4: final states (t=63 -> parity 1)
  k_states<<<128, 256, 0, stream>>>(h0f + 32768, h1f + 32768, out + 65536000UL);
}

// Round 3
// 1821.773 us; speedup vs baseline: 1.4346x; 1.3895x over previous
//
#include <hip/hip_runtime.h>

// Seq2SeqDecoder: 2-layer GRU (reset_after) + logit projection, MI355X/gfx950.
// B=32 T=64 V=32000 E=512 H=1024.
//   phase 0: transpose-convert weights to bf16 [N][K]; build xin bf16; init states
//   phase 1: MX0 = xin @ k0t + b0[0]                  (bf16 MFMA GEMM, 19.3 GF)
//   phase 2: ONE cooperative persistent kernel runs the whole recurrence:
//            66 pipeline steps with a CUSTOM agent-scope grid barrier
//            (cg::grid.sync() measured ~33us/step in R2 -> replaced)
//   phase 3: logits = seq1 @ Wdt + bd                 (134.2 GF) -> d_out
//   phase 4: final states -> d_out tail

typedef __attribute__((ext_vector_type(8))) short bf16x8;
typedef __attribute__((ext_vector_type(4))) float f32x4;
typedef unsigned short u16;

#define CHAIN_BLOCKS 192

__device__ __forceinline__ u16 f2bf(float f) {
  unsigned int x = __float_as_uint(f);
  x += 0x7fffu + ((x >> 16) & 1u);   // RNE
  return (u16)(x >> 16);
}

// Monotonic-counter grid barrier. Arrival = fetch_add(RELEASE, agent)
// (flushes this XCD's dirty L2 lines to the coherence point). Spin = RELAXED
// agent loads (read-through, NO per-poll invalidate). One ACQUIRE load after
// the spin drops stale L2 lines before we read other blocks' h-updates.
__device__ __forceinline__ void gridbar(unsigned* cnt, unsigned& phase) {
  __syncthreads();
  if (threadIdx.x == 0) {
    phase += 1;
    __hip_atomic_fetch_add(cnt, 1u, __ATOMIC_RELEASE, __HIP_MEMORY_SCOPE_AGENT);
    const unsigned target = CHAIN_BLOCKS * phase;
    while (__hip_atomic_load(cnt, __ATOMIC_RELAXED, __HIP_MEMORY_SCOPE_AGENT) <
           target)
      __builtin_amdgcn_s_sleep(1);
    (void)__hip_atomic_load(cnt, __ATOMIC_ACQUIRE, __HIP_MEMORY_SCOPE_AGENT);
  }
  __syncthreads();
}

// ---- transpose + convert: in f32 [R][C] -> out bf16 [C][R] ----------------
__global__ void k_tconv(const float* __restrict__ in, u16* __restrict__ out,
                        int R, int C) {
  __shared__ float t[32][33];
  int tx = threadIdx.x, ty = threadIdx.y;          // 32 x 8
  int c0 = blockIdx.x * 32, r0 = blockIdx.y * 32;
#pragma unroll
  for (int i = 0; i < 4; ++i)
    t[ty + i * 8][tx] = in[(long)(r0 + ty + i * 8) * C + c0 + tx];
  __syncthreads();
#pragma unroll
  for (int i = 0; i < 4; ++i)
    out[(long)(c0 + ty + i * 8) * R + r0 + tx] = f2bf(t[tx][ty + i * 8]);
}

// ---- xin[bt][0:512]=emb[X[bt]], [512:1536]=state[1][b]  (bf16) ------------
__global__ void k_embed(const int* __restrict__ X, const float* __restrict__ state,
                        const float* __restrict__ emb, u16* __restrict__ xin) {
  int bt = blockIdx.x;
  int b = bt >> 6;
  int tok = X[bt];
  const float* er = emb + (long)tok * 512;
  const float* cr = state + 32 * 1024 + b * 1024;  // state[-1] == state[1]
  for (int c = threadIdx.x; c < 1536; c += 256) {
    float v = (c < 512) ? er[c] : cr[c - 512];
    xin[(long)bt * 1536 + c] = f2bf(v);
  }
}

// ---- init: H0 slot0 = bf16(state[0]); parity-1 slots hold h(-1) -----------
__global__ void k_init(const float* __restrict__ state, u16* __restrict__ H0,
                       u16* __restrict__ H1, float* __restrict__ h0f,
                       float* __restrict__ h1f, unsigned* __restrict__ cnt) {
  int i = blockIdx.x * 256 + threadIdx.x;          // grid 128 -> 32768
  if (i == 0) *cnt = 0u;                           // barrier counter reset
  float v0 = state[i], v1 = state[32768 + i];
  H0[i] = f2bf(v0);             // H0 slot 0  (holds h0(-1))
  h0f[32768 + i] = v0;          // parity 1
  H1[32768 + i] = f2bf(v1);     // parity 1   (holds h1(-1))
  h1f[32768 + i] = v1;
}

// ---- bf16 GEMM: C[M,N]f32 = A[M,K] @ Bt[N,K]^T + bias[N] ------------------
// 128x128 tile, BK=32, 256 thr = 4 waves (wave quadrant 64x64, 4x4 mfma tiles)
__global__ void k_gemm(const u16* __restrict__ A, const u16* __restrict__ Bt,
                       const float* __restrict__ bias, float* __restrict__ C,
                       int M, int N, int K) {
  __shared__ u16 As[128][40];
  __shared__ u16 Bs[128][40];
  int tid = threadIdx.x;
  int w = tid >> 6, l = tid & 63;
  int ln = l & 15, lk = l >> 4;
  int r0 = blockIdx.y * 128, c0 = blockIdx.x * 128;
  int qr = (w & 1) * 64, qc = (w >> 1) * 64;
  int sr = tid >> 1, sc = (tid & 1) * 16;
  const u16* Ap = A + (long)(r0 + sr) * K + sc;
  const u16* Bp = Bt + (long)(c0 + sr) * K + sc;
  f32x4 acc[4][4] = {};
  for (int kt = 0; kt < K; kt += 32) {
    bf16x8 a0 = *(const bf16x8*)(Ap + kt);
    bf16x8 a1 = *(const bf16x8*)(Ap + kt + 8);
    bf16x8 b0 = *(const bf16x8*)(Bp + kt);
    bf16x8 b1 = *(const bf16x8*)(Bp + kt + 8);
    __syncthreads();
    *(bf16x8*)(&As[sr][sc]) = a0;  *(bf16x8*)(&As[sr][sc + 8]) = a1;
    *(bf16x8*)(&Bs[sr][sc]) = b0;  *(bf16x8*)(&Bs[sr][sc + 8]) = b1;
    __syncthreads();
    bf16x8 af[4], bfv[4];
#pragma unroll
    for (int mt = 0; mt < 4; ++mt)
      af[mt] = *(const bf16x8*)(&As[qr + mt * 16 + ln][lk * 8]);
#pragma unroll
    for (int nt = 0; nt < 4; ++nt)
      bfv[nt] = *(const bf16x8*)(&Bs[qc + nt * 16 + ln][lk * 8]);
#pragma unroll
    for (int mt = 0; mt < 4; ++mt)
#pragma unroll
      for (int nt = 0; nt < 4; ++nt)
        acc[mt][nt] = __builtin_amdgcn_mfma_f32_16x16x32_bf16(
            af[mt], bfv[nt], acc[mt][nt], 0, 0, 0);
  }
#pragma unroll
  for (int mt = 0; mt < 4; ++mt)
#pragma unroll
    for (int nt = 0; nt < 4; ++nt)
#pragma unroll
      for (int r = 0; r < 4; ++r) {
        int row = r0 + qr + mt * 16 + lk * 4 + r;
        int col = c0 + qc + nt * 16 + ln;
        C[(long)row * N + col] = acc[mt][nt][r] + bias[col];
      }
}

// ---- persistent cooperative recurrence kernel -----------------------------
// grid 192: blocks [0,64)=L0, [64,128)=MX1, [128,192)=L1; each owns 16 h-cols.
// 66 pipeline steps: L0 at t=s, MX1 at t=s-1, L1 at t=s-2; gridbar between.
// Per step per block: [32,1024]bf16 @ [1024,48]bf16 -> [32,48]f32 (+gate).
// H0: 4-slot rotation, slot (i&3) holds h0(i-1). h0f/h1f/H1/MX1: parity t&1.
__global__ void __launch_bounds__(256, 1)
k_chain(const u16* __restrict__ rk0t, const u16* __restrict__ k1t,
        const u16* __restrict__ rk1t, const float* __restrict__ MX0,
        const float* __restrict__ b0, const float* __restrict__ b1,
        float* __restrict__ MX1, u16* __restrict__ H0, u16* __restrict__ H1,
        float* __restrict__ h0f, float* __restrict__ h1f,
        u16* __restrict__ seq1, unsigned* __restrict__ cnt) {
  __shared__ float red[2][3][4][64];
  const int blk = blockIdx.x;
  const int type = blk >> 6;          // 0:L0  1:MX1  2:L1
  const int cb = blk & 63;
  const int j0 = cb << 4;             // 16 h-cols per block
  const int tid = threadIdx.x;
  const int w = tid >> 6, l = tid & 63;
  const int ln = l & 15, lk = l >> 4;
  const int rt = w & 1, kh = w >> 1;  // row-tile (16 rows), K-half (512)
  unsigned phase = 0;

  const u16* Wt = (type == 0) ? rk0t : (type == 1) ? k1t : rk1t;
  const u16* wp = Wt + (long)(j0 + ln) * 1024 + kh * 512 + lk * 8;

  for (int s = 0; s < 66; ++s) {
    const int tt = (type == 0) ? s : (type == 1) ? s - 1 : s - 2;
    const bool active = (tt >= 0) && (tt < 64);
    f32x4 acc[3] = {};
    if (active) {
      const u16* Ab =
          (type == 0) ? H0 + (long)(tt & 3) * 32768 :          // h0(t-1)
          (type == 1) ? H0 + (long)((tt + 1) & 3) * 32768 :    // h0(t)
                        H1 + (long)((tt + 1) & 1) * 32768;     // h1(t-1)
      const u16* hp = Ab + (rt * 16 + ln) * 1024 + kh * 512 + lk * 8;
#pragma unroll 4
      for (int ks = 0; ks < 16; ++ks) {
        bf16x8 a = *(const bf16x8*)(hp + ks * 32);
#pragma unroll
        for (int g = 0; g < 3; ++g) {
          bf16x8 bv = *(const bf16x8*)(wp + ((long)g << 20) + ks * 32);
          acc[g] = __builtin_amdgcn_mfma_f32_16x16x32_bf16(a, bv, acc[g], 0, 0, 0);
        }
      }
      if (kh == 1) {
#pragma unroll
        for (int g = 0; g < 3; ++g)
#pragma unroll
          for (int r = 0; r < 4; ++r)
            red[rt][g][r][l] = acc[g][r];
      }
    }
    __syncthreads();
    if (active && kh == 0) {
#pragma unroll
      for (int r = 0; r < 4; ++r) {
        const int row = rt * 16 + lk * 4 + r;    // batch b
        const int j = j0 + ln;
        float mz = acc[0][r] + red[rt][0][r][l];
        float mr = acc[1][r] + red[rt][1][r][l];
        float mh = acc[2][r] + red[rt][2][r][l];
        if (type == 1) {
          float* o = MX1 + (long)(tt & 1) * 98304 + (long)row * 3072;
          o[j]        = mz + b1[j];
          o[1024 + j] = mr + b1[1024 + j];
          o[2048 + j] = mh + b1[2048 + j];
        } else {
          const float* bias = (type == 0) ? b0 + 3072 : b1 + 3072;  // b[1]
          const float* mx =
              (type == 0) ? MX0 + ((long)row * 64 + tt) * 3072
                          : MX1 + (long)(tt & 1) * 98304 + (long)row * 3072;
          float miz = mz + bias[j];
          float mir = mr + bias[1024 + j];
          float mih = mh + bias[2048 + j];
          float z  = 1.f / (1.f + expf(-(mx[j] + miz)));
          float rg = 1.f / (1.f + expf(-(mx[1024 + j] + mir)));
          float hh = tanhf(mx[2048 + j] + rg * mih);
          float* hf = (type == 0) ? h0f : h1f;
          float hold = hf[(long)((tt + 1) & 1) * 32768 + row * 1024 + j];
          float hn = z * hold + (1.f - z) * hh;
          hf[(long)(tt & 1) * 32768 + row * 1024 + j] = hn;
          u16 hb = f2bf(hn);
          if (type == 0) {
            H0[(long)((tt + 1) & 3) * 32768 + row * 1024 + j] = hb;   // h0(t)
          } else {
            H1[(long)(tt & 1) * 32768 + row * 1024 + j] = hb;         // h1(t)
            seq1[((long)row * 64 + tt) * 1024 + j] = hb;
          }
        }
      }
    }
    gridbar(cnt, phase);
  }
}

__global__ void k_states(const float* __restrict__ h0, const float* __restrict__ h1,
                         float* __restrict__ out) {
  int i = blockIdx.x * 256 + threadIdx.x;        // grid 128
  out[i] = h0[i];
  out[32768 + i] = h1[i];
}

extern "C" void kernel_launch(void* const* d_in, const int* in_sizes, int n_in,
                              void* d_out, int out_size, void* d_ws, size_t ws_size,
                              hipStream_t stream) {
  const int*   X     = (const int*)  d_in[0];
  const float* state = (const float*)d_in[1];
  const float* emb   = (const float*)d_in[2];
  const float* k0    = (const float*)d_in[3];
  const float* rk0   = (const float*)d_in[4];
  const float* b0    = (const float*)d_in[5];
  const float* k1    = (const float*)d_in[6];
  const float* rk1   = (const float*)d_in[7];
  const float* b1    = (const float*)d_in[8];
  const float* Wd    = (const float*)d_in[9];
  const float* bd    = (const float*)d_in[10];
  float* out = (float*)d_out;

  char* p = (char*)d_ws;
  size_t off = 0;
  auto alloc = [&](size_t bytes) {
    char* r = p + off;
    off += (bytes + 255) & ~(size_t)255;
    return r;
  };
  u16* k0t  = (u16*)alloc(3072UL * 1536 * 2);
  u16* rk0t = (u16*)alloc(3072UL * 1024 * 2);
  u16* k1t  = (u16*)alloc(3072UL * 1024 * 2);
  u16* rk1t = (u16*)alloc(3072UL * 1024 * 2);
  u16* Wdt  = (u16*)alloc(32000UL * 1024 * 2);
  u16* xin  = (u16*)alloc(2048UL * 1536 * 2);
  float* MX0 = (float*)alloc(2048UL * 3072 * 4);
  float* MX1 = (float*)alloc(2UL * 32 * 3072 * 4);
  u16* H0   = (u16*)alloc(4UL * 32768 * 2);      // 4-slot rotation
  u16* H1   = (u16*)alloc(2UL * 32768 * 2);
  float* h0f = (float*)alloc(2UL * 32768 * 4);
  float* h1f = (float*)alloc(2UL * 32768 * 4);
  u16* seq1 = (u16*)alloc(2048UL * 1024 * 2);
  unsigned* cnt = (unsigned*)alloc(256);
  if (off > ws_size) return;   // ws too small -> poison output signature

  dim3 tb(32, 8);
  k_tconv<<<dim3(3072 / 32, 1536 / 32), tb, 0, stream>>>(k0, k0t, 1536, 3072);
  k_tconv<<<dim3(3072 / 32, 1024 / 32), tb, 0, stream>>>(rk0, rk0t, 1024, 3072);
  k_tconv<<<dim3(3072 / 32, 1024 / 32), tb, 0, stream>>>(k1, k1t, 1024, 3072);
  k_tconv<<<dim3(3072 / 32, 1024 / 32), tb, 0, stream>>>(rk1, rk1t, 1024, 3072);
  k_tconv<<<dim3(32000 / 32, 1024 / 32), tb, 0, stream>>>(Wd, Wdt, 1024, 32000);
  k_embed<<<2048, 256, 0, stream>>>(X, state, emb, xin);
  k_init<<<128, 256, 0, stream>>>(state, H0, H1, h0f, h1f, cnt);

  // phase 1: MX0 = xin @ k0t + b0[0]
  k_gemm<<<dim3(24, 16), 256, 0, stream>>>(xin, k0t, b0, MX0, 2048, 3072, 1536);

  // phase 2: full recurrence in one cooperative kernel (custom barrier)
  {
    void* args[] = {(void*)&rk0t, (void*)&k1t, (void*)&rk1t, (void*)&MX0,
                    (void*)&b0,   (void*)&b1,  (void*)&MX1,  (void*)&H0,
                    (void*)&H1,   (void*)&h0f, (void*)&h1f,  (void*)&seq1,
                    (void*)&cnt};
    hipLaunchCooperativeKernel((void*)k_chain, dim3(CHAIN_BLOCKS), dim3(256),
                               args, 0, stream);
  }

  // phase 3: logits = seq1 @ Wdt + bd
  k_gemm<<<dim3(32000 / 128, 16), 256, 0, stream>>>(seq1, Wdt, bd, out,
                                                    2048, 32000, 1024);
  // phase 4: final states (t=63 -> parity 1)
  k_states<<<128, 256, 0, stream>>>(h0f + 32768, h1f + 32768, out + 65536000UL);
}

// Round 4
// 1606.968 us; speedup vs baseline: 1.6263x; 1.1337x over previous
//
#include <hip/hip_runtime.h>

// Seq2SeqDecoder: 2-layer GRU (reset_after) + logit projection, MI355X/gfx950.
// B=32 T=64 V=32000 E=512 H=1024.
//   phase 0: transpose-convert weights to bf16 [N][K]; build xin bf16; init states
//   phase 1: MX0 = xin @ k0t + b0[0]                  (bf16 MFMA GEMM, 19.3 GF)
//   phase 2: ONE cooperative persistent kernel runs the whole recurrence:
//            66 pipeline steps with a TWO-LEVEL agent-scope grid barrier
//            (R3: single-counter barrier = 192 serialized same-line RMWs/step
//             + poller interference -> ~20us/step; this round: 16 leaf lines
//             x12 + 16-RMW root, pollers only on root)
//   phase 3: logits = seq1 @ Wdt + bd                 (134.2 GF) -> d_out
//   phase 4: final states -> d_out tail

typedef __attribute__((ext_vector_type(8))) short bf16x8;
typedef __attribute__((ext_vector_type(4))) float f32x4;
typedef unsigned short u16;

#define CHAIN_BLOCKS 192
#define BAR_GROUPS 16
#define BAR_GROUP_SZ 12          // CHAIN_BLOCKS / BAR_GROUPS
#define BAR_WORDS (17 * 64)      // 16 leaf lines (256B apart) + root line

__device__ __forceinline__ u16 f2bf(float f) {
  unsigned int x = __float_as_uint(f);
  x += 0x7fffu + ((x >> 16) & 1u);   // RNE
  return (u16)(x >> 16);
}

// Two-level monotonic grid barrier.
//  leaf[g*64] += 1 (RELEASE: wbl2 publishes this block's h-stores to L3)
//  12th arriver of group -> root += 1 (RELEASE)
//  all blocks poll root (RELAXED, s_sleep(2)) until root == 16*phase
//  one ACQUIRE load (buffer_inv) before reading other blocks' data.
__device__ __forceinline__ void gridbar(unsigned* bar, unsigned phase) {
  __syncthreads();
  if (threadIdx.x == 0) {
    unsigned* leaf = bar + (blockIdx.x & (BAR_GROUPS - 1)) * 64;
    unsigned* root = bar + BAR_GROUPS * 64;
    unsigned prev = __hip_atomic_fetch_add(leaf, 1u, __ATOMIC_RELEASE,
                                           __HIP_MEMORY_SCOPE_AGENT);
    if ((prev + 1u) % BAR_GROUP_SZ == 0u)
      __hip_atomic_fetch_add(root, 1u, __ATOMIC_RELEASE,
                             __HIP_MEMORY_SCOPE_AGENT);
    const unsigned target = BAR_GROUPS * phase;
    while (__hip_atomic_load(root, __ATOMIC_RELAXED,
                             __HIP_MEMORY_SCOPE_AGENT) < target)
      __builtin_amdgcn_s_sleep(2);
    (void)__hip_atomic_load(root, __ATOMIC_ACQUIRE, __HIP_MEMORY_SCOPE_AGENT);
  }
  __syncthreads();
}

// ---- transpose + convert: in f32 [R][C] -> out bf16 [C][R] ----------------
__global__ void k_tconv(const float* __restrict__ in, u16* __restrict__ out,
                        int R, int C) {
  __shared__ float t[32][33];
  int tx = threadIdx.x, ty = threadIdx.y;          // 32 x 8
  int c0 = blockIdx.x * 32, r0 = blockIdx.y * 32;
#pragma unroll
  for (int i = 0; i < 4; ++i)
    t[ty + i * 8][tx] = in[(long)(r0 + ty + i * 8) * C + c0 + tx];
  __syncthreads();
#pragma unroll
  for (int i = 0; i < 4; ++i)
    out[(long)(c0 + ty + i * 8) * R + r0 + tx] = f2bf(t[tx][ty + i * 8]);
}

// ---- xin[bt][0:512]=emb[X[bt]], [512:1536]=state[1][b]  (bf16) ------------
__global__ void k_embed(const int* __restrict__ X, const float* __restrict__ state,
                        const float* __restrict__ emb, u16* __restrict__ xin) {
  int bt = blockIdx.x;
  int b = bt >> 6;
  int tok = X[bt];
  const float* er = emb + (long)tok * 512;
  const float* cr = state + 32 * 1024 + b * 1024;  // state[-1] == state[1]
  for (int c = threadIdx.x; c < 1536; c += 256) {
    float v = (c < 512) ? er[c] : cr[c - 512];
    xin[(long)bt * 1536 + c] = f2bf(v);
  }
}

// ---- init: H0 slot0 = bf16(state[0]); parity-1 slots hold h(-1) -----------
__global__ void k_init(const float* __restrict__ state, u16* __restrict__ H0,
                       u16* __restrict__ H1, float* __restrict__ h0f,
                       float* __restrict__ h1f, unsigned* __restrict__ bar) {
  int i = blockIdx.x * 256 + threadIdx.x;          // grid 128 -> 32768
  if (i < BAR_WORDS) bar[i] = 0u;                  // barrier counters reset
  float v0 = state[i], v1 = state[32768 + i];
  H0[i] = f2bf(v0);             // H0 slot 0  (holds h0(-1))
  h0f[32768 + i] = v0;          // parity 1
  H1[32768 + i] = f2bf(v1);     // parity 1   (holds h1(-1))
  h1f[32768 + i] = v1;
}

// ---- bf16 GEMM: C[M,N]f32 = A[M,K] @ Bt[N,K]^T + bias[N] ------------------
// 128x128 tile, BK=32, 256 thr = 4 waves (wave quadrant 64x64, 4x4 mfma tiles)
__global__ void k_gemm(const u16* __restrict__ A, const u16* __restrict__ Bt,
                       const float* __restrict__ bias, float* __restrict__ C,
                       int M, int N, int K) {
  __shared__ u16 As[128][40];
  __shared__ u16 Bs[128][40];
  int tid = threadIdx.x;
  int w = tid >> 6, l = tid & 63;
  int ln = l & 15, lk = l >> 4;
  int r0 = blockIdx.y * 128, c0 = blockIdx.x * 128;
  int qr = (w & 1) * 64, qc = (w >> 1) * 64;
  int sr = tid >> 1, sc = (tid & 1) * 16;
  const u16* Ap = A + (long)(r0 + sr) * K + sc;
  const u16* Bp = Bt + (long)(c0 + sr) * K + sc;
  f32x4 acc[4][4] = {};
  for (int kt = 0; kt < K; kt += 32) {
    bf16x8 a0 = *(const bf16x8*)(Ap + kt);
    bf16x8 a1 = *(const bf16x8*)(Ap + kt + 8);
    bf16x8 b0 = *(const bf16x8*)(Bp + kt);
    bf16x8 b1 = *(const bf16x8*)(Bp + kt + 8);
    __syncthreads();
    *(bf16x8*)(&As[sr][sc]) = a0;  *(bf16x8*)(&As[sr][sc + 8]) = a1;
    *(bf16x8*)(&Bs[sr][sc]) = b0;  *(bf16x8*)(&Bs[sr][sc + 8]) = b1;
    __syncthreads();
    bf16x8 af[4], bfv[4];
#pragma unroll
    for (int mt = 0; mt < 4; ++mt)
      af[mt] = *(const bf16x8*)(&As[qr + mt * 16 + ln][lk * 8]);
#pragma unroll
    for (int nt = 0; nt < 4; ++nt)
      bfv[nt] = *(const bf16x8*)(&Bs[qc + nt * 16 + ln][lk * 8]);
#pragma unroll
    for (int mt = 0; mt < 4; ++mt)
#pragma unroll
      for (int nt = 0; nt < 4; ++nt)
        acc[mt][nt] = __builtin_amdgcn_mfma_f32_16x16x32_bf16(
            af[mt], bfv[nt], acc[mt][nt], 0, 0, 0);
  }
#pragma unroll
  for (int mt = 0; mt < 4; ++mt)
#pragma unroll
    for (int nt = 0; nt < 4; ++nt)
#pragma unroll
      for (int r = 0; r < 4; ++r) {
        int row = r0 + qr + mt * 16 + lk * 4 + r;
        int col = c0 + qc + nt * 16 + ln;
        C[(long)row * N + col] = acc[mt][nt][r] + bias[col];
      }
}

// ---- persistent cooperative recurrence kernel -----------------------------
// grid 192: blocks [0,64)=L0, [64,128)=MX1, [128,192)=L1; each owns 16 h-cols.
// 66 pipeline steps: L0 at t=s, MX1 at t=s-1, L1 at t=s-2; gridbar between.
// Per step per block: [32,1024]bf16 @ [1024,48]bf16 -> [32,48]f32 (+gate).
// H0: 4-slot rotation, slot (i&3) holds h0(i-1). h0f/h1f/H1/MX1: parity t&1.
__global__ void __launch_bounds__(256, 1)
k_chain(const u16* __restrict__ rk0t, const u16* __restrict__ k1t,
        const u16* __restrict__ rk1t, const float* __restrict__ MX0,
        const float* __restrict__ b0, const float* __restrict__ b1,
        float* __restrict__ MX1, u16* __restrict__ H0, u16* __restrict__ H1,
        float* __restrict__ h0f, float* __restrict__ h1f,
        u16* __restrict__ seq1, unsigned* __restrict__ bar) {
  __shared__ float red[2][3][4][64];
  const int blk = blockIdx.x;
  const int type = blk >> 6;          // 0:L0  1:MX1  2:L1
  const int cb = blk & 63;
  const int j0 = cb << 4;             // 16 h-cols per block
  const int tid = threadIdx.x;
  const int w = tid >> 6, l = tid & 63;
  const int ln = l & 15, lk = l >> 4;
  const int rt = w & 1, kh = w >> 1;  // row-tile (16 rows), K-half (512)

  const u16* Wt = (type == 0) ? rk0t : (type == 1) ? k1t : rk1t;
  const u16* wp = Wt + (long)(j0 + ln) * 1024 + kh * 512 + lk * 8;

  for (int s = 0; s < 66; ++s) {
    const int tt = (type == 0) ? s : (type == 1) ? s - 1 : s - 2;
    const bool active = (tt >= 0) && (tt < 64);
    f32x4 acc[3] = {};
    if (active) {
      const u16* Ab =
          (type == 0) ? H0 + (long)(tt & 3) * 32768 :          // h0(t-1)
          (type == 1) ? H0 + (long)((tt + 1) & 3) * 32768 :    // h0(t)
                        H1 + (long)((tt + 1) & 1) * 32768;     // h1(t-1)
      const u16* hp = Ab + (rt * 16 + ln) * 1024 + kh * 512 + lk * 8;
#pragma unroll 4
      for (int ks = 0; ks < 16; ++ks) {
        bf16x8 a = *(const bf16x8*)(hp + ks * 32);
#pragma unroll
        for (int g = 0; g < 3; ++g) {
          bf16x8 bv = *(const bf16x8*)(wp + ((long)g << 20) + ks * 32);
          acc[g] = __builtin_amdgcn_mfma_f32_16x16x32_bf16(a, bv, acc[g], 0, 0, 0);
        }
      }
      if (kh == 1) {
#pragma unroll
        for (int g = 0; g < 3; ++g)
#pragma unroll
          for (int r = 0; r < 4; ++r)
            red[rt][g][r][l] = acc[g][r];
      }
    }
    __syncthreads();
    if (active && kh == 0) {
#pragma unroll
      for (int r = 0; r < 4; ++r) {
        const int row = rt * 16 + lk * 4 + r;    // batch b
        const int j = j0 + ln;
        float mz = acc[0][r] + red[rt][0][r][l];
        float mr = acc[1][r] + red[rt][1][r][l];
        float mh = acc[2][r] + red[rt][2][r][l];
        if (type == 1) {
          float* o = MX1 + (long)(tt & 1) * 98304 + (long)row * 3072;
          o[j]        = mz + b1[j];
          o[1024 + j] = mr + b1[1024 + j];
          o[2048 + j] = mh + b1[2048 + j];
        } else {
          const float* bias = (type == 0) ? b0 + 3072 : b1 + 3072;  // b[1]
          const float* mx =
              (type == 0) ? MX0 + ((long)row * 64 + tt) * 3072
                          : MX1 + (long)(tt & 1) * 98304 + (long)row * 3072;
          float miz = mz + bias[j];
          float mir = mr + bias[1024 + j];
          float mih = mh + bias[2048 + j];
          float z  = 1.f / (1.f + expf(-(mx[j] + miz)));
          float rg = 1.f / (1.f + expf(-(mx[1024 + j] + mir)));
          float hh = tanhf(mx[2048 + j] + rg * mih);
          float* hf = (type == 0) ? h0f : h1f;
          float hold = hf[(long)((tt + 1) & 1) * 32768 + row * 1024 + j];
          float hn = z * hold + (1.f - z) * hh;
          hf[(long)(tt & 1) * 32768 + row * 1024 + j] = hn;
          u16 hb = f2bf(hn);
          if (type == 0) {
            H0[(long)((tt + 1) & 3) * 32768 + row * 1024 + j] = hb;   // h0(t)
          } else {
            H1[(long)(tt & 1) * 32768 + row * 1024 + j] = hb;         // h1(t)
            seq1[((long)row * 64 + tt) * 1024 + j] = hb;
          }
        }
      }
    }
    gridbar(bar, (unsigned)(s + 1));
  }
}

__global__ void k_states(const float* __restrict__ h0, const float* __restrict__ h1,
                         float* __restrict__ out) {
  int i = blockIdx.x * 256 + threadIdx.x;        // grid 128
  out[i] = h0[i];
  out[32768 + i] = h1[i];
}

extern "C" void kernel_launch(void* const* d_in, const int* in_sizes, int n_in,
                              void* d_out, int out_size, void* d_ws, size_t ws_size,
                              hipStream_t stream) {
  const int*   X     = (const int*)  d_in[0];
  const float* state = (const float*)d_in[1];
  const float* emb   = (const float*)d_in[2];
  const float* k0    = (const float*)d_in[3];
  const float* rk0   = (const float*)d_in[4];
  const float* b0    = (const float*)d_in[5];
  const float* k1    = (const float*)d_in[6];
  const float* rk1   = (const float*)d_in[7];
  const float* b1    = (const float*)d_in[8];
  const float* Wd    = (const float*)d_in[9];
  const float* bd    = (const float*)d_in[10];
  float* out = (float*)d_out;

  char* p = (char*)d_ws;
  size_t off = 0;
  auto alloc = [&](size_t bytes) {
    char* r = p + off;
    off += (bytes + 255) & ~(size_t)255;
    return r;
  };
  u16* k0t  = (u16*)alloc(3072UL * 1536 * 2);
  u16* rk0t = (u16*)alloc(3072UL * 1024 * 2);
  u16* k1t  = (u16*)alloc(3072UL * 1024 * 2);
  u16* rk1t = (u16*)alloc(3072UL * 1024 * 2);
  u16* Wdt  = (u16*)alloc(32000UL * 1024 * 2);
  u16* xin  = (u16*)alloc(2048UL * 1536 * 2);
  float* MX0 = (float*)alloc(2048UL * 3072 * 4);
  float* MX1 = (float*)alloc(2UL * 32 * 3072 * 4);
  u16* H0   = (u16*)alloc(4UL * 32768 * 2);      // 4-slot rotation
  u16* H1   = (u16*)alloc(2UL * 32768 * 2);
  float* h0f = (float*)alloc(2UL * 32768 * 4);
  float* h1f = (float*)alloc(2UL * 32768 * 4);
  u16* seq1 = (u16*)alloc(2048UL * 1024 * 2);
  unsigned* bar = (unsigned*)alloc(BAR_WORDS * 4);
  if (off > ws_size) return;   // ws too small -> poison output signature

  dim3 tb(32, 8);
  k_tconv<<<dim3(3072 / 32, 1536 / 32), tb, 0, stream>>>(k0, k0t, 1536, 3072);
  k_tconv<<<dim3(3072 / 32, 1024 / 32), tb, 0, stream>>>(rk0, rk0t, 1024, 3072);
  k_tconv<<<dim3(3072 / 32, 1024 / 32), tb, 0, stream>>>(k1, k1t, 1024, 3072);
  k_tconv<<<dim3(3072 / 32, 1024 / 32), tb, 0, stream>>>(rk1, rk1t, 1024, 3072);
  k_tconv<<<dim3(32000 / 32, 1024 / 32), tb, 0, stream>>>(Wd, Wdt, 1024, 32000);
  k_embed<<<2048, 256, 0, stream>>>(X, state, emb, xin);
  k_init<<<128, 256, 0, stream>>>(state, H0, H1, h0f, h1f, bar);

  // phase 1: MX0 = xin @ k0t + b0[0]
  k_gemm<<<dim3(24, 16), 256, 0, stream>>>(xin, k0t, b0, MX0, 2048, 3072, 1536);

  // phase 2: full recurrence in one cooperative kernel (2-level barrier)
  {
    void* args[] = {(void*)&rk0t, (void*)&k1t, (void*)&rk1t, (void*)&MX0,
                    (void*)&b0,   (void*)&b1,  (void*)&MX1,  (void*)&H0,
                    (void*)&H1,   (void*)&h0f, (void*)&h1f,  (void*)&seq1,
                    (void*)&bar};
    hipLaunchCooperativeKernel((void*)k_chain, dim3(CHAIN_BLOCKS), dim3(256),
                               args, 0, stream);
  }

  // phase 3: logits = seq1 @ Wdt + bd
  k_gemm<<<dim3(32000 / 128, 16), 256, 0, stream>>>(seq1, Wdt, bd, out,
                                                    2048, 32000, 1024);
  // phase 4: final states (t=63 -> parity 1)
  k_states<<<128, 256, 0, stream>>>(h0f + 32768, h1f + 32768, out + 65536000UL);
}

// Round 5
// 1424.995 us; speedup vs baseline: 1.8340x; 1.1277x over previous
//
#include <hip/hip_runtime.h>

// Seq2SeqDecoder: 2-layer GRU (reset_after) + logit projection, MI355X/gfx950.
// B=32 T=64 V=32000 E=512 H=1024.
//   phase 0: transpose-convert weights to bf16 [N][K]; build xin bf16; init states
//   phase 1: MX0 = xin @ k0t + b0[0]                  (bf16 MFMA GEMM, 19.3 GF)
//   phase 2: ONE cooperative persistent kernel runs the whole recurrence.
//     R3: release/acquire barrier   -> 22.6 us/step
//     R4: + 2-level arrival tree    -> 19.2 us/step (RMW contention NOT dominant)
//     R5: fence-FREE barrier. Cross-block data (H0/H1/MX1) moves via relaxed
//         agent-scope (sc1) loads/stores = read/write-through at L3. No
//         buffer_wbl2 / buffer_inv in the loop -> weights stay L2-resident.
//         Ordering: __syncthreads drains vmcnt (sc1 store-ack = visible at L3)
//         before arrival RMW. Poll fanout: 16 leaders poll root, 11/group poll
//         per-group go line.
//   phase 3: logits = seq1 @ Wdt + bd                 (134.2 GF) -> d_out
//   phase 4: final states -> d_out tail

typedef __attribute__((ext_vector_type(8))) short bf16x8;
typedef __attribute__((ext_vector_type(4))) float f32x4;
typedef __attribute__((ext_vector_type(2))) unsigned long long u64x2;
typedef unsigned short u16;
typedef unsigned int u32;

#define CHAIN_BLOCKS 192
#define BAR_GROUPS 16
#define BAR_GROUP_SZ 12          // CHAIN_BLOCKS / BAR_GROUPS
#define BAR_WORDS (33 * 64)      // 16 leaf + 1 root + 16 go lines, 256B apart

__device__ __forceinline__ u16 f2bf(float f) {
  unsigned int x = __float_as_uint(f);
  x += 0x7fffu + ((x >> 16) & 1u);   // RNE
  return (u16)(x >> 16);
}

// ---- agent-scope (sc1) access helpers: bypass L2, L3 is coherence point ----
__device__ __forceinline__ bf16x8 aload16(const u16* p) {
  unsigned long long lo = __hip_atomic_load((const unsigned long long*)p,
      __ATOMIC_RELAXED, __HIP_MEMORY_SCOPE_AGENT);
  unsigned long long hi = __hip_atomic_load((const unsigned long long*)(p + 4),
      __ATOMIC_RELAXED, __HIP_MEMORY_SCOPE_AGENT);
  union { u64x2 u; bf16x8 v; } t;
  t.u.x = lo; t.u.y = hi;
  return t.v;
}
__device__ __forceinline__ float aloadf(const float* p) {
  return __uint_as_float(__hip_atomic_load((const u32*)p, __ATOMIC_RELAXED,
                                           __HIP_MEMORY_SCOPE_AGENT));
}
__device__ __forceinline__ void astoref(float* p, float v) {
  __hip_atomic_store((u32*)p, __float_as_uint(v), __ATOMIC_RELAXED,
                     __HIP_MEMORY_SCOPE_AGENT);
}
__device__ __forceinline__ void astore32(u16* p, u32 v) {
  __hip_atomic_store((u32*)p, v, __ATOMIC_RELAXED, __HIP_MEMORY_SCOPE_AGENT);
}

// Fence-free grid barrier (monotonic counters, reset by k_init each launch).
// Entry: every wave drains vmcnt (sc1 stores acked => visible at L3), then
// block barrier. tid0: leaf RMW; 12th arriver bumps root, polls root (16
// pollers on that line), writes go[g]; others poll go[g] (11 pollers/line).
__device__ __forceinline__ void gridbar(u32* bar, u32 phase) {
  asm volatile("s_waitcnt vmcnt(0)" ::: "memory");
  __syncthreads();
  if (threadIdx.x == 0) {
    const int g = blockIdx.x & (BAR_GROUPS - 1);
    u32* leaf = bar + g * 64;
    u32* root = bar + BAR_GROUPS * 64;
    u32* go   = bar + (BAR_GROUPS + 1 + g) * 64;
    u32 prev = __hip_atomic_fetch_add(leaf, 1u, __ATOMIC_RELAXED,
                                      __HIP_MEMORY_SCOPE_AGENT);
    if ((prev + 1u) % BAR_GROUP_SZ == 0u) {
      __hip_atomic_fetch_add(root, 1u, __ATOMIC_RELAXED,
                             __HIP_MEMORY_SCOPE_AGENT);
      while (__hip_atomic_load(root, __ATOMIC_RELAXED,
                               __HIP_MEMORY_SCOPE_AGENT) < BAR_GROUPS * phase)
        __builtin_amdgcn_s_sleep(1);
      __hip_atomic_store(go, phase, __ATOMIC_RELAXED,
                         __HIP_MEMORY_SCOPE_AGENT);
    } else {
      while (__hip_atomic_load(go, __ATOMIC_RELAXED,
                               __HIP_MEMORY_SCOPE_AGENT) < phase)
        __builtin_amdgcn_s_sleep(1);
    }
  }
  __syncthreads();
}

// ---- transpose + convert: in f32 [R][C] -> out bf16 [C][R] ----------------
__global__ void k_tconv(const float* __restrict__ in, u16* __restrict__ out,
                        int R, int C) {
  __shared__ float t[32][33];
  int tx = threadIdx.x, ty = threadIdx.y;          // 32 x 8
  int c0 = blockIdx.x * 32, r0 = blockIdx.y * 32;
#pragma unroll
  for (int i = 0; i < 4; ++i)
    t[ty + i * 8][tx] = in[(long)(r0 + ty + i * 8) * C + c0 + tx];
  __syncthreads();
#pragma unroll
  for (int i = 0; i < 4; ++i)
    out[(long)(c0 + ty + i * 8) * R + r0 + tx] = f2bf(t[tx][ty + i * 8]);
}

// ---- xin[bt][0:512]=emb[X[bt]], [512:1536]=state[1][b]  (bf16) ------------
__global__ void k_embed(const int* __restrict__ X, const float* __restrict__ state,
                        const float* __restrict__ emb, u16* __restrict__ xin) {
  int bt = blockIdx.x;
  int b = bt >> 6;
  int tok = X[bt];
  const float* er = emb + (long)tok * 512;
  const float* cr = state + 32 * 1024 + b * 1024;  // state[-1] == state[1]
  for (int c = threadIdx.x; c < 1536; c += 256) {
    float v = (c < 512) ? er[c] : cr[c - 512];
    xin[(long)bt * 1536 + c] = f2bf(v);
  }
}

// ---- init: H0 slot0 = bf16(state[0]); parity-1 slots hold h(-1) -----------
__global__ void k_init(const float* __restrict__ state, u16* __restrict__ H0,
                       u16* __restrict__ H1, float* __restrict__ h0f,
                       float* __restrict__ h1f, u32* __restrict__ bar) {
  int i = blockIdx.x * 256 + threadIdx.x;          // grid 128 -> 32768
  if (i < BAR_WORDS) bar[i] = 0u;                  // barrier counters reset
  float v0 = state[i], v1 = state[32768 + i];
  H0[i] = f2bf(v0);             // H0 slot 0  (holds h0(-1))
  h0f[32768 + i] = v0;          // parity 1
  H1[32768 + i] = f2bf(v1);     // parity 1   (holds h1(-1))
  h1f[32768 + i] = v1;
}

// ---- bf16 GEMM: C[M,N]f32 = A[M,K] @ Bt[N,K]^T + bias[N] ------------------
// 128x128 tile, BK=32, 256 thr = 4 waves (wave quadrant 64x64, 4x4 mfma tiles)
__global__ void k_gemm(const u16* __restrict__ A, const u16* __restrict__ Bt,
                       const float* __restrict__ bias, float* __restrict__ C,
                       int M, int N, int K) {
  __shared__ u16 As[128][40];
  __shared__ u16 Bs[128][40];
  int tid = threadIdx.x;
  int w = tid >> 6, l = tid & 63;
  int ln = l & 15, lk = l >> 4;
  int r0 = blockIdx.y * 128, c0 = blockIdx.x * 128;
  int qr = (w & 1) * 64, qc = (w >> 1) * 64;
  int sr = tid >> 1, sc = (tid & 1) * 16;
  const u16* Ap = A + (long)(r0 + sr) * K + sc;
  const u16* Bp = Bt + (long)(c0 + sr) * K + sc;
  f32x4 acc[4][4] = {};
  for (int kt = 0; kt < K; kt += 32) {
    bf16x8 a0 = *(const bf16x8*)(Ap + kt);
    bf16x8 a1 = *(const bf16x8*)(Ap + kt + 8);
    bf16x8 b0 = *(const bf16x8*)(Bp + kt);
    bf16x8 b1 = *(const bf16x8*)(Bp + kt + 8);
    __syncthreads();
    *(bf16x8*)(&As[sr][sc]) = a0;  *(bf16x8*)(&As[sr][sc + 8]) = a1;
    *(bf16x8*)(&Bs[sr][sc]) = b0;  *(bf16x8*)(&Bs[sr][sc + 8]) = b1;
    __syncthreads();
    bf16x8 af[4], bfv[4];
#pragma unroll
    for (int mt = 0; mt < 4; ++mt)
      af[mt] = *(const bf16x8*)(&As[qr + mt * 16 + ln][lk * 8]);
#pragma unroll
    for (int nt = 0; nt < 4; ++nt)
      bfv[nt] = *(const bf16x8*)(&Bs[qc + nt * 16 + ln][lk * 8]);
#pragma unroll
    for (int mt = 0; mt < 4; ++mt)
#pragma unroll
      for (int nt = 0; nt < 4; ++nt)
        acc[mt][nt] = __builtin_amdgcn_mfma_f32_16x16x32_bf16(
            af[mt], bfv[nt], acc[mt][nt], 0, 0, 0);
  }
#pragma unroll
  for (int mt = 0; mt < 4; ++mt)
#pragma unroll
    for (int nt = 0; nt < 4; ++nt)
#pragma unroll
      for (int r = 0; r < 4; ++r) {
        int row = r0 + qr + mt * 16 + lk * 4 + r;
        int col = c0 + qc + nt * 16 + ln;
        C[(long)row * N + col] = acc[mt][nt][r] + bias[col];
      }
}

// ---- persistent cooperative recurrence kernel -----------------------------
// grid 192: blocks [0,64)=L0, [64,128)=MX1, [128,192)=L1; each owns 16 h-cols.
// 66 pipeline steps: L0 at t=s, MX1 at t=s-1, L1 at t=s-2; gridbar between.
// Per step per block: [32,1024]bf16 @ [1024,48]bf16 -> [32,48]f32 (+gate).
// Cross-block arrays (H0 bf16 4-slot, H1 bf16 2-slot, MX1 f32 2-slot) use
// sc1 agent-scope access; weights/MX0/h0f/h1f/seq1 use normal cached access.
__global__ void __launch_bounds__(256, 1)
k_chain(const u16* __restrict__ rk0t, const u16* __restrict__ k1t,
        const u16* __restrict__ rk1t, const float* __restrict__ MX0,
        const float* __restrict__ b0, const float* __restrict__ b1,
        float* __restrict__ MX1, u16* __restrict__ H0, u16* __restrict__ H1,
        float* __restrict__ h0f, float* __restrict__ h1f,
        u16* __restrict__ seq1, u32* __restrict__ bar) {
  __shared__ float red[2][3][4][64];
  __shared__ u16 hbS[32][16];
  const int blk = blockIdx.x;
  const int type = blk >> 6;          // 0:L0  1:MX1  2:L1
  const int cb = blk & 63;
  const int j0 = cb << 4;             // 16 h-cols per block
  const int tid = threadIdx.x;
  const int w = tid >> 6, l = tid & 63;
  const int ln = l & 15, lk = l >> 4;
  const int rt = w & 1, kh = w >> 1;  // row-tile (16 rows), K-half (512)

  const u16* Wt = (type == 0) ? rk0t : (type == 1) ? k1t : rk1t;
  const u16* wp = Wt + (long)(j0 + ln) * 1024 + kh * 512 + lk * 8;

  for (int s = 0; s < 66; ++s) {
    const int tt = (type == 0) ? s : (type == 1) ? s - 1 : s - 2;
    const bool active = (tt >= 0) && (tt < 64);
    f32x4 acc[3] = {};
    if (active) {
      const u16* Ab =
          (type == 0) ? H0 + (long)(tt & 3) * 32768 :          // h0(t-1)
          (type == 1) ? H0 + (long)((tt + 1) & 3) * 32768 :    // h0(t)
                        H1 + (long)((tt + 1) & 1) * 32768;     // h1(t-1)
      const u16* hp = Ab + (rt * 16 + ln) * 1024 + kh * 512 + lk * 8;
#pragma unroll 4
      for (int ks = 0; ks < 16; ++ks) {
        bf16x8 a = aload16(hp + ks * 32);                      // sc1: fresh
#pragma unroll
        for (int g = 0; g < 3; ++g) {
          bf16x8 bv = *(const bf16x8*)(wp + ((long)g << 20) + ks * 32);
          acc[g] = __builtin_amdgcn_mfma_f32_16x16x32_bf16(a, bv, acc[g], 0, 0, 0);
        }
      }
      if (kh == 1) {
#pragma unroll
        for (int g = 0; g < 3; ++g)
#pragma unroll
          for (int r = 0; r < 4; ++r)
            red[rt][g][r][l] = acc[g][r];
      }
    }
    __syncthreads();
    if (active && kh == 0) {
#pragma unroll
      for (int r = 0; r < 4; ++r) {
        const int row = rt * 16 + lk * 4 + r;    // batch b
        const int j = j0 + ln;
        float mz = acc[0][r] + red[rt][0][r][l];
        float mr = acc[1][r] + red[rt][1][r][l];
        float mh = acc[2][r] + red[rt][2][r][l];
        if (type == 1) {
          float* o = MX1 + (long)(tt & 1) * 98304 + (long)row * 3072;
          astoref(o + j,        mz + b1[j]);
          astoref(o + 1024 + j, mr + b1[1024 + j]);
          astoref(o + 2048 + j, mh + b1[2048 + j]);
        } else {
          const float* bias = (type == 0) ? b0 + 3072 : b1 + 3072;  // b[1]
          float mxz, mxr, mxh;
          if (type == 0) {
            const float* mx = MX0 + ((long)row * 64 + tt) * 3072;
            mxz = mx[j]; mxr = mx[1024 + j]; mxh = mx[2048 + j];
          } else {
            const float* mx = MX1 + (long)(tt & 1) * 98304 + (long)row * 3072;
            mxz = aloadf(mx + j);
            mxr = aloadf(mx + 1024 + j);
            mxh = aloadf(mx + 2048 + j);
          }
          float miz = mz + bias[j];
          float mir = mr + bias[1024 + j];
          float mih = mh + bias[2048 + j];
          float z  = 1.f / (1.f + expf(-(mxz + miz)));
          float rg = 1.f / (1.f + expf(-(mxr + mir)));
          float hh = tanhf(mxh + rg * mih);
          float* hf = (type == 0) ? h0f : h1f;
          float hold = hf[(long)((tt + 1) & 1) * 32768 + row * 1024 + j];
          float hn = z * hold + (1.f - z) * hh;
          hf[(long)(tt & 1) * 32768 + row * 1024 + j] = hn;    // private
          hbS[row][ln] = f2bf(hn);                             // stage bf16
        }
      }
    }
    if (type != 1) {
      __syncthreads();
      if (active) {
        // cooperative u32 writeout of the staged 32x16 bf16 tile
        const int row = tid >> 3, cp = tid & 7;
        const u32 v = ((const u32*)&hbS[row][0])[cp];
        const int j = j0 + cp * 2;
        if (type == 0) {
          astore32(&H0[(long)((tt + 1) & 3) * 32768 + row * 1024 + j], v);
        } else {
          astore32(&H1[(long)(tt & 1) * 32768 + row * 1024 + j], v);
          *(u32*)&seq1[((long)row * 64 + tt) * 1024 + j] = v;  // normal store
        }
      }
    }
    gridbar(bar, (u32)(s + 1));
  }
}

__global__ void k_states(const float* __restrict__ h0, const float* __restrict__ h1,
                         float* __restrict__ out) {
  int i = blockIdx.x * 256 + threadIdx.x;        // grid 128
  out[i] = h0[i];
  out[32768 + i] = h1[i];
}

extern "C" void kernel_launch(void* const* d_in, const int* in_sizes, int n_in,
                              void* d_out, int out_size, void* d_ws, size_t ws_size,
                              hipStream_t stream) {
  const int*   X     = (const int*)  d_in[0];
  const float* state = (const float*)d_in[1];
  const float* emb   = (const float*)d_in[2];
  const float* k0    = (const float*)d_in[3];
  const float* rk0   = (const float*)d_in[4];
  const float* b0    = (const float*)d_in[5];
  const float* k1    = (const float*)d_in[6];
  const float* rk1   = (const float*)d_in[7];
  const float* b1    = (const float*)d_in[8];
  const float* Wd    = (const float*)d_in[9];
  const float* bd    = (const float*)d_in[10];
  float* out = (float*)d_out;

  char* p = (char*)d_ws;
  size_t off = 0;
  auto alloc = [&](size_t bytes) {
    char* r = p + off;
    off += (bytes + 255) & ~(size_t)255;
    return r;
  };
  u16* k0t  = (u16*)alloc(3072UL * 1536 * 2);
  u16* rk0t = (u16*)alloc(3072UL * 1024 * 2);
  u16* k1t  = (u16*)alloc(3072UL * 1024 * 2);
  u16* rk1t = (u16*)alloc(3072UL * 1024 * 2);
  u16* Wdt  = (u16*)alloc(32000UL * 1024 * 2);
  u16* xin  = (u16*)alloc(2048UL * 1536 * 2);
  float* MX0 = (float*)alloc(2048UL * 3072 * 4);
  float* MX1 = (float*)alloc(2UL * 32 * 3072 * 4);
  u16* H0   = (u16*)alloc(4UL * 32768 * 2);      // 4-slot rotation
  u16* H1   = (u16*)alloc(2UL * 32768 * 2);
  float* h0f = (float*)alloc(2UL * 32768 * 4);
  float* h1f = (float*)alloc(2UL * 32768 * 4);
  u16* seq1 = (u16*)alloc(2048UL * 1024 * 2);
  u32* bar  = (u32*)alloc(BAR_WORDS * 4);
  if (off > ws_size) return;   // ws too small -> poison output signature

  dim3 tb(32, 8);
  k_tconv<<<dim3(3072 / 32, 1536 / 32), tb, 0, stream>>>(k0, k0t, 1536, 3072);
  k_tconv<<<dim3(3072 / 32, 1024 / 32), tb, 0, stream>>>(rk0, rk0t, 1024, 3072);
  k_tconv<<<dim3(3072 / 32, 1024 / 32), tb, 0, stream>>>(k1, k1t, 1024, 3072);
  k_tconv<<<dim3(3072 / 32, 1024 / 32), tb, 0, stream>>>(rk1, rk1t, 1024, 3072);
  k_tconv<<<dim3(32000 / 32, 1024 / 32), tb, 0, stream>>>(Wd, Wdt, 1024, 32000);
  k_embed<<<2048, 256, 0, stream>>>(X, state, emb, xin);
  k_init<<<128, 256, 0, stream>>>(state, H0, H1, h0f, h1f, bar);

  // phase 1: MX0 = xin @ k0t + b0[0]
  k_gemm<<<dim3(24, 16), 256, 0, stream>>>(xin, k0t, b0, MX0, 2048, 3072, 1536);

  // phase 2: full recurrence in one cooperative kernel (fence-free barrier)
  {
    void* args[] = {(void*)&rk0t, (void*)&k1t, (void*)&rk1t, (void*)&MX0,
                    (void*)&b0,   (void*)&b1,  (void*)&MX1,  (void*)&H0,
                    (void*)&H1,   (void*)&h0f, (void*)&h1f,  (void*)&seq1,
                    (void*)&bar};
    hipLaunchCooperativeKernel((void*)k_chain, dim3(CHAIN_BLOCKS), dim3(256),
                               args, 0, stream);
  }

  // phase 3: logits = seq1 @ Wdt + bd
  k_gemm<<<dim3(32000 / 128, 16), 256, 0, stream>>>(seq1, Wdt, bd, out,
                                                    2048, 32000, 1024);
  // phase 4: final states (t=63 -> parity 1)
  k_states<<<128, 256, 0, stream>>>(h0f + 32768, h1f + 32768, out + 65536000UL);
}